// Round 1
// baseline (324.485 us; speedup 1.0000x reference)
//
#include <hip/hip_runtime.h>
#include <hip/hip_bf16.h>

// SelfAttentionHead: B=4, S=4096, D=256, fp32 in/out.
// out = qp + softmax(tril_mul(qp kp^T / 16)) @ vp, with masked entries = 0 (not -inf).
// Decomposition: causal flash-attn + (S-1-q)*e^{-M} in Z + e^{-M}*SuffV[q] in numerator.

#define S_LEN 4096
#define D_DIM 256
#define B_N 4

typedef __bf16 bf16x8 __attribute__((ext_vector_type(8)));
typedef float f32x4 __attribute__((ext_vector_type(4)));

__device__ __forceinline__ unsigned short f2bf_u(float f) {
  unsigned u = __float_as_uint(f);
  u += 0x7fffu + ((u >> 16) & 1u);
  return (unsigned short)(u >> 16);
}

// ---------------- WT[j][k] = bf16(W[k][j]) for the 3 weight matrices ----------------
__global__ __launch_bounds__(256) void wt_kernel(
    const float* __restrict__ Wq, const float* __restrict__ Wk, const float* __restrict__ Wv,
    unsigned short* __restrict__ WTq, unsigned short* __restrict__ WTk, unsigned short* __restrict__ WTv) {
  int j = blockIdx.x & 255;
  int wsel = blockIdx.x >> 8;
  const float* W = wsel == 0 ? Wq : (wsel == 1 ? Wk : Wv);
  unsigned short* WT = wsel == 0 ? WTq : (wsel == 1 ? WTk : WTv);
  int k = threadIdx.x;
  WT[j * 256 + k] = f2bf_u(W[k * 256 + j]);
}

// ---------------- Projection GEMM: C[16384,256] = X @ W + b ----------------
// mode 0 (q): outf=qp_f32, outb=qp_bf16 scaled by 1/16
// mode 1 (k): outb=kp_bf16
// mode 2 (v): outf=vp_f32, outb=vpT_bf16 [B][D][S]
__global__ __launch_bounds__(256) void proj_kernel(
    const float* __restrict__ X, const unsigned short* __restrict__ WT,
    const float* __restrict__ bias, float* __restrict__ outf,
    unsigned short* __restrict__ outb, int mode) {
  int rt = blockIdx.x;
  int tid = threadIdx.x;
  int w = tid >> 6, l = tid & 63, g = l >> 4, lm = l & 15;
  int arow = rt * 64 + w * 16 + lm;

  f32x4 acc[16];
#pragma unroll
  for (int i = 0; i < 16; i++) acc[i] = (f32x4){0.f, 0.f, 0.f, 0.f};

#pragma unroll
  for (int kb = 0; kb < 256; kb += 32) {
    const float* ap = X + arow * 256 + kb + 8 * g;
    float4 a0 = *(const float4*)ap;
    float4 a1 = *(const float4*)(ap + 4);
    bf16x8 af;
    af[0] = (__bf16)a0.x; af[1] = (__bf16)a0.y; af[2] = (__bf16)a0.z; af[3] = (__bf16)a0.w;
    af[4] = (__bf16)a1.x; af[5] = (__bf16)a1.y; af[6] = (__bf16)a1.z; af[7] = (__bf16)a1.w;
#pragma unroll
    for (int nt = 0; nt < 16; nt++) {
      bf16x8 bf = *(const bf16x8*)(WT + (nt * 16 + lm) * 256 + kb + 8 * g);
      acc[nt] = __builtin_amdgcn_mfma_f32_16x16x32_bf16(af, bf, acc[nt], 0, 0, 0);
    }
  }

#pragma unroll
  for (int nt = 0; nt < 16; nt++) {
    int col = nt * 16 + lm;
    float bb = bias[col];
#pragma unroll
    for (int r = 0; r < 4; r++) {
      int orow = rt * 64 + w * 16 + 4 * g + r;
      float v = acc[nt][r] + bb;
      int idx = orow * 256 + col;
      if (mode == 0) {
        outf[idx] = v;
        outb[idx] = f2bf_u(v * 0.0625f);  // fold 1/sqrt(D)=1/16 into Q
      } else if (mode == 1) {
        outb[idx] = f2bf_u(v);
      } else {
        outf[idx] = v;
        int b = orow >> 12, s = orow & 4095;
        outb[(b * 256 + col) * 4096 + s] = f2bf_u(v);  // vpT[b][d][s]
      }
    }
  }
}

// ---------------- Suffix-sum of vp over k (exclusive): SuffV[b,q,:] = sum_{k>q} vp[b,k,:] ----------------
__global__ __launch_bounds__(256) void scan1(const float* __restrict__ vpf, float* __restrict__ ctot) {
  int c = blockIdx.x, b = blockIdx.y, d = threadIdx.x;
  const float* base = vpf + (b * 4096 + c * 128) * 256 + d;
  float acc = 0.f;
#pragma unroll 4
  for (int r = 0; r < 128; r++) acc += base[r * 256];
  ctot[(b * 32 + c) * 256 + d] = acc;
}

__global__ __launch_bounds__(256) void scan2(const float* __restrict__ vpf, const float* __restrict__ ctot,
                                             float* __restrict__ suffv) {
  int c = blockIdx.x, b = blockIdx.y, d = threadIdx.x;
  float acc = 0.f;
  for (int c2 = c + 1; c2 < 32; c2++) acc += ctot[(b * 32 + c2) * 256 + d];
  const float* base = vpf + (b * 4096 + c * 128) * 256 + d;
  float* sbase = suffv + (b * 4096 + c * 128) * 256 + d;
  for (int r = 127; r >= 0; r--) {
    sbase[r * 256] = acc;
    acc += base[r * 256];
  }
}

// ---------------- Flash attention (lower triangle) + masked-zero correction ----------------
// block = 256 threads (4 waves), handles (b, q-tile of 64). LDS: K[64][264], Vt[256][72], P[4][16][72].
#define ATTN_LDS (64 * 264 * 2 + 256 * 72 * 2 + 4 * 16 * 72 * 2)

__global__ __launch_bounds__(256) void attn_kernel(
    const unsigned short* __restrict__ qpb, const unsigned short* __restrict__ kpb,
    const unsigned short* __restrict__ vptb, const float* __restrict__ qpf,
    const float* __restrict__ suffv, float* __restrict__ out) {
  extern __shared__ char smem[];
  unsigned short(*Klds)[264] = (unsigned short(*)[264])smem;
  unsigned short(*Vlds)[72] = (unsigned short(*)[72])(smem + 64 * 264 * 2);
  unsigned short(*Plds)[16][72] = (unsigned short(*)[16][72])(smem + 64 * 264 * 2 + 256 * 72 * 2);

  int bid = blockIdx.x;
  int b = bid & 3;
  int qt = 63 - (bid >> 2);  // heaviest q-tiles first
  int tid = threadIdx.x, w = tid >> 6, l = tid & 63, g = l >> 4, lm = l & 15;

  // Q fragments (rows qt*64 + w*16 + lm), pre-scaled by 1/16
  bf16x8 qa[8];
  int qrow_a = qt * 64 + w * 16 + lm;
  const unsigned short* qbase = qpb + (b * 4096 + qrow_a) * 256;
#pragma unroll
  for (int d0 = 0; d0 < 8; d0++) qa[d0] = *(const bf16x8*)(qbase + d0 * 32 + 8 * g);

  float m[4], Z[4];
  f32x4 O[16];
#pragma unroll
  for (int r = 0; r < 4; r++) { m[r] = -1e30f; Z[r] = 0.f; }
#pragma unroll
  for (int i = 0; i < 16; i++) O[i] = (f32x4){0.f, 0.f, 0.f, 0.f};

  for (int kt = 0; kt <= qt; kt++) {
    // ---- stage K tile [64][256] and Vt tile [256][64] ----
    const unsigned short* ksrc = kpb + (b * 4096 + kt * 64) * 256;
#pragma unroll
    for (int i = 0; i < 8; i++) {
      int idx = i * 256 + tid;
      int row = idx >> 5, cx = idx & 31;
      *(uint4*)&Klds[row][cx * 8] = *(const uint4*)(ksrc + row * 256 + cx * 8);
    }
    const unsigned short* vsrc = vptb + (b * 256) * 4096 + kt * 64;
#pragma unroll
    for (int i = 0; i < 8; i++) {
      int idx = i * 256 + tid;
      int row = idx >> 3, cx = idx & 7;
      *(uint4*)&Vlds[row][cx * 8] = *(const uint4*)(vsrc + row * 4096 + cx * 8);
    }
    __syncthreads();

    // ---- QK^T: 16x64 scores per wave ----
    f32x4 s[4];
#pragma unroll
    for (int jt = 0; jt < 4; jt++) s[jt] = (f32x4){0.f, 0.f, 0.f, 0.f};
#pragma unroll
    for (int d0 = 0; d0 < 8; d0++) {
#pragma unroll
      for (int jt = 0; jt < 4; jt++) {
        bf16x8 kf = *(const bf16x8*)&Klds[jt * 16 + lm][d0 * 32 + 8 * g];
        s[jt] = __builtin_amdgcn_mfma_f32_16x16x32_bf16(qa[d0], kf, s[jt], 0, 0, 0);
      }
    }

    if (kt == qt) {  // diagonal tile: strict upper triangle -> -inf (excluded in-loop)
#pragma unroll
      for (int jt = 0; jt < 4; jt++)
#pragma unroll
        for (int r = 0; r < 4; r++)
          if (jt * 16 + lm > w * 16 + 4 * g + r) s[jt][r] = -1e30f;
    }

    // ---- online softmax (rows 4g+r, reduce across 16 lanes of group g) ----
    float mx[4], rs[4], sc[4], mn[4];
#pragma unroll
    for (int r = 0; r < 4; r++)
      mx[r] = fmaxf(fmaxf(s[0][r], s[1][r]), fmaxf(s[2][r], s[3][r]));
#pragma unroll
    for (int off = 1; off < 16; off <<= 1)
#pragma unroll
      for (int r = 0; r < 4; r++) mx[r] = fmaxf(mx[r], __shfl_xor(mx[r], off, 16));
#pragma unroll
    for (int r = 0; r < 4; r++) {
      mn[r] = fmaxf(m[r], mx[r]);
      sc[r] = __expf(m[r] - mn[r]);
      m[r] = mn[r];
      rs[r] = 0.f;
    }
#pragma unroll
    for (int jt = 0; jt < 4; jt++)
#pragma unroll
      for (int r = 0; r < 4; r++) {
        float p = __expf(s[jt][r] - mn[r]);
        rs[r] += p;
        Plds[w][4 * g + r][jt * 16 + lm] = f2bf_u(p);
      }
#pragma unroll
    for (int off = 1; off < 16; off <<= 1)
#pragma unroll
      for (int r = 0; r < 4; r++) rs[r] += __shfl_xor(rs[r], off, 16);
#pragma unroll
    for (int r = 0; r < 4; r++) Z[r] = Z[r] * sc[r] + rs[r];
#pragma unroll
    for (int ct = 0; ct < 16; ct++)
#pragma unroll
      for (int r = 0; r < 4; r++) O[ct][r] *= sc[r];
    __syncthreads();  // P visible to own wave; also orders vs LDS reuse

    // ---- PV: O[16x256] += P[16x64] @ V[64x256] ----
    bf16x8 pa[2];
    pa[0] = *(const bf16x8*)&Plds[w][lm][8 * g];
    pa[1] = *(const bf16x8*)&Plds[w][lm][32 + 8 * g];
#pragma unroll
    for (int ks = 0; ks < 2; ks++)
#pragma unroll
      for (int dt = 0; dt < 16; dt++) {
        bf16x8 vf = *(const bf16x8*)&Vlds[dt * 16 + lm][ks * 32 + 8 * g];
        O[dt] = __builtin_amdgcn_mfma_f32_16x16x32_bf16(pa[ks], vf, O[dt], 0, 0, 0);
      }
    __syncthreads();
  }

  // ---- epilogue: masked-zero correction + qp add ----
#pragma unroll
  for (int r = 0; r < 4; r++) {
    int q = qt * 64 + w * 16 + 4 * g + r;
    int nmask = 4095 - q;
    float mf, scl, corr, Zf;
    if (nmask > 0) {
      mf = fmaxf(m[r], 0.f);
      scl = __expf(m[r] - mf);
      float e0 = __expf(-mf);
      Zf = Z[r] * scl + (float)nmask * e0;
      corr = e0;
    } else {
      scl = 1.f; corr = 0.f; Zf = Z[r];
    }
    float rZ = 1.f / Zf;
#pragma unroll
    for (int dt = 0; dt < 16; dt++) {
      int idx = (b * 4096 + q) * 256 + dt * 16 + lm;
      out[idx] = qpf[idx] + (O[dt][r] * scl + corr * suffv[idx]) * rZ;
    }
  }
}

// ---------------- launch ----------------
extern "C" void kernel_launch(void* const* d_in, const int* in_sizes, int n_in,
                              void* d_out, int out_size, void* d_ws, size_t ws_size,
                              hipStream_t stream) {
  const float* v_in = (const float*)d_in[0];
  const float* k_in = (const float*)d_in[1];
  const float* q_in = (const float*)d_in[2];
  const float* Wq = (const float*)d_in[3];
  const float* bq = (const float*)d_in[4];
  const float* Wk = (const float*)d_in[5];
  const float* bk = (const float*)d_in[6];
  const float* Wv = (const float*)d_in[7];
  const float* bv = (const float*)d_in[8];
  float* out = (float*)d_out;

  char* p = (char*)d_ws;
  float* qpf = (float*)(p + 0);                        // 16 MB
  float* vpf = (float*)(p + 16777216);                 // 16 MB
  float* suffv = (float*)(p + 33554432);               // 16 MB
  unsigned short* qpb = (unsigned short*)(p + 50331648);   // 8 MB (scaled 1/16)
  unsigned short* kpb = (unsigned short*)(p + 58720256);   // 8 MB
  unsigned short* vptb = (unsigned short*)(p + 67108864);  // 8 MB, [B][D][S]
  unsigned short* WTq = (unsigned short*)(p + 75497472);
  unsigned short* WTk = (unsigned short*)(p + 75628544);
  unsigned short* WTv = (unsigned short*)(p + 75759616);
  float* ctot = (float*)(p + 75890688);                // 128 KB

  hipFuncSetAttribute((const void*)attn_kernel,
                      hipFuncAttributeMaxDynamicSharedMemorySize, ATTN_LDS);

  wt_kernel<<<768, 256, 0, stream>>>(Wq, Wk, Wv, WTq, WTk, WTv);
  proj_kernel<<<256, 256, 0, stream>>>(q_in, WTq, bq, qpf, qpb, 0);
  proj_kernel<<<256, 256, 0, stream>>>(k_in, WTk, bk, nullptr, kpb, 1);
  proj_kernel<<<256, 256, 0, stream>>>(v_in, WTv, bv, vpf, vptb, 2);
  scan1<<<dim3(32, 4), 256, 0, stream>>>(vpf, ctot);
  scan2<<<dim3(32, 4), 256, 0, stream>>>(vpf, ctot, suffv);
  attn_kernel<<<256, 256, ATTN_LDS, stream>>>(qpb, kpb, vptb, qpf, suffv, out);
}